// Round 1
// baseline (781.187 us; speedup 1.0000x reference)
//
#include <hip/hip_runtime.h>
#include <math.h>

#define BD 8
#define DD 128
#define NN 32768
#define CHUNK 64
#define EPSZ 1e-8f

__device__ __forceinline__ float phi(float x) {
    // elu(x)+1 : x+1 for x>0, exp(x) for x<=0
    return x > 0.0f ? x + 1.0f : __expf(x);
}

// ---------------------------------------------------------------------------
// Kernel 1: KV[b][d][e] = sum_n phi(K[b][d][n]) * V[b][e][n]
//           KS[b][d]    = sum_n phi(K[b][d][n])
// grid: (NSPLIT=64, B). Each WG: 8x8 register tile of 128x128 KV, 512 tokens.
// LDS layout [d][64] rotated by 4*(d>>3) so broadcast reads are conflict-free.
// ---------------------------------------------------------------------------
__global__ __launch_bounds__(256, 2) void k1_kv(const float* __restrict__ K,
                                                const float* __restrict__ V,
                                                float* __restrict__ KV,
                                                float* __restrict__ KS) {
    __shared__ float ks[DD][CHUNK];
    __shared__ float vs[DD][CHUNK];
    const int b = blockIdx.y;
    const int tokens = NN / gridDim.x;      // 512
    const int nbeg = blockIdx.x * tokens;
    const int tid = threadIdx.x;
    const int ty = tid >> 4;                // 0..15  (d-block of KV)
    const int tx = tid & 15;                // 0..15  (e-block of KV)
    const float* Kb = K + (size_t)b * DD * NN;
    const float* Vb = V + (size_t)b * DD * NN;

    float acc[8][8];
#pragma unroll
    for (int r = 0; r < 8; ++r)
#pragma unroll
        for (int s = 0; s < 8; ++s) acc[r][s] = 0.0f;
    float sk[8] = {0.f, 0.f, 0.f, 0.f, 0.f, 0.f, 0.f, 0.f};

    const int drow = tid >> 4;              // staging row group
    const int c4 = (tid & 15) * 4;          // staging col (float4)

    for (int c0 = 0; c0 < tokens; c0 += CHUNK) {
        const int n0 = nbeg + c0;
        __syncthreads();                    // previous chunk's reads done
#pragma unroll
        for (int p = 0; p < 8; ++p) {
            const int d = p * 16 + drow;
            const float4 kq = *reinterpret_cast<const float4*>(Kb + (size_t)d * NN + n0 + c4);
            const float4 vq = *reinterpret_cast<const float4*>(Vb + (size_t)d * NN + n0 + c4);
            const int cc = (c4 + 4 * (d >> 3)) & 63;    // rotated, stays 16B-aligned
            *reinterpret_cast<float4*>(&ks[d][cc]) =
                make_float4(phi(kq.x), phi(kq.y), phi(kq.z), phi(kq.w));
            *reinterpret_cast<float4*>(&vs[d][cc]) = vq;
        }
        __syncthreads();
#pragma unroll 2
        for (int n = 0; n < CHUNK; ++n) {
            float pk[8], vv[8];
            const int ck = (n + 4 * ty) & 63;   // (d>>3)==ty for d=8ty+r
            const int cv = (n + 4 * tx) & 63;
#pragma unroll
            for (int r = 0; r < 8; ++r) pk[r] = ks[8 * ty + r][ck];
#pragma unroll
            for (int s = 0; s < 8; ++s) vv[s] = vs[8 * tx + s][cv];
#pragma unroll
            for (int r = 0; r < 8; ++r) {
                sk[r] += pk[r];
#pragma unroll
                for (int s = 0; s < 8; ++s) acc[r][s] += pk[r] * vv[s];
            }
        }
    }

    float* KVb = KV + (size_t)b * DD * DD;
#pragma unroll
    for (int r = 0; r < 8; ++r)
#pragma unroll
        for (int s = 0; s < 8; ++s)
            atomicAdd(&KVb[(8 * ty + r) * DD + 8 * tx + s], acc[r][s]);
    if (tx == 0) {
#pragma unroll
        for (int r = 0; r < 8; ++r) atomicAdd(&KS[b * DD + 8 * ty + r], sk[r]);
    }
}

// ---------------------------------------------------------------------------
// Kernel 2: out[b][e][n] = z[b][n] * sum_d phi(Q[b][d][n]) * KV[b][d][e]
//           z = 1/(sum_d phi(Q[b][d][n])*KS[b][d] + eps)
// grid: (SPLIT2=32, B). KV resident in LDS; q-chunks double-buffered via regs.
// ---------------------------------------------------------------------------
__global__ __launch_bounds__(256, 1) void k2_out(const float* __restrict__ Q,
                                                 const float* __restrict__ KVg,
                                                 const float* __restrict__ KSg,
                                                 float* __restrict__ Out) {
    __shared__ float kv[DD][DD];            // 64 KB
    __shared__ float qs[DD][CHUNK];         // 32 KB, rotated like k1
    __shared__ float kss[DD];
    __shared__ float zpart[4][CHUNK];
    __shared__ float zs[CHUNK];
    const int b = blockIdx.y;
    const int tokens = NN / gridDim.x;      // 1024
    const int nbeg = blockIdx.x * tokens;
    const int tid = threadIdx.x;
    const int ty = tid >> 4;                // n-block: 4 tokens
    const int tx = tid & 15;                // e-block: 8 cols
    const float* Qb = Q + (size_t)b * DD * NN;
    const float* KVb = KVg + (size_t)b * DD * DD;
    float* Ob = Out + (size_t)b * DD * NN;

    // load KV + KS into LDS
#pragma unroll
    for (int i = 0; i < 16; ++i) {
        const int idx = (i * 256 + tid) * 4;
        *reinterpret_cast<float4*>(&kv[idx >> 7][idx & 127]) =
            *reinterpret_cast<const float4*>(KVb + idx);
    }
    if (tid < DD) kss[tid] = KSg[b * DD + tid];

    const int drow = tid >> 4;
    const int c4 = (tid & 15) * 4;

    float4 pre[8];
#pragma unroll
    for (int p = 0; p < 8; ++p) {
        const int d = p * 16 + drow;
        pre[p] = *reinterpret_cast<const float4*>(Qb + (size_t)d * NN + nbeg + c4);
    }

    const int nchunks = tokens / CHUNK;     // 16
    for (int c = 0; c < nchunks; ++c) {
        const int n0 = nbeg + c * CHUNK;
        __syncthreads();                    // prev chunk reads done / kv ready
#pragma unroll
        for (int p = 0; p < 8; ++p) {
            const int d = p * 16 + drow;
            const int cc = (c4 + 4 * (d >> 3)) & 63;
            const float4 vq = pre[p];
            *reinterpret_cast<float4*>(&qs[d][cc]) =
                make_float4(phi(vq.x), phi(vq.y), phi(vq.z), phi(vq.w));
        }
        __syncthreads();
        // prefetch next chunk into registers (hidden under compute below)
        if (c + 1 < nchunks) {
#pragma unroll
            for (int p = 0; p < 8; ++p) {
                const int d = p * 16 + drow;
                pre[p] = *reinterpret_cast<const float4*>(Qb + (size_t)d * NN + n0 + CHUNK + c4);
            }
        }
        // Z: 4-way split partial dot with KS
        {
            const int n = tid & 63;
            const int qq = tid >> 6;
            float s = 0.0f;
#pragma unroll
            for (int j = 0; j < 32; ++j) {
                const int d = qq * 32 + j;
                s += qs[d][(n + 4 * (d >> 3)) & 63] * kss[d];
            }
            zpart[qq][n] = s;
        }
        __syncthreads();
        if (tid < CHUNK) {
            zs[tid] = 1.0f / (zpart[0][tid] + zpart[1][tid] + zpart[2][tid] + zpart[3][tid] + EPSZ);
        }
        __syncthreads();
        // main: acc[n-sub 4][e-sub 8] over d
        float acc[4][8];
#pragma unroll
        for (int i = 0; i < 4; ++i)
#pragma unroll
            for (int s = 0; s < 8; ++s) acc[i][s] = 0.0f;
#pragma unroll 2
        for (int d = 0; d < DD; ++d) {
            const float4 pq = *reinterpret_cast<const float4*>(&qs[d][(4 * ty + 4 * (d >> 3)) & 63]);
            const float4 k0 = *reinterpret_cast<const float4*>(&kv[d][8 * tx]);
            const float4 k1 = *reinterpret_cast<const float4*>(&kv[d][8 * tx + 4]);
            const float pqa[4] = {pq.x, pq.y, pq.z, pq.w};
            const float kva[8] = {k0.x, k0.y, k0.z, k0.w, k1.x, k1.y, k1.z, k1.w};
#pragma unroll
            for (int i = 0; i < 4; ++i)
#pragma unroll
                for (int s = 0; s < 8; ++s) acc[i][s] += pqa[i] * kva[s];
        }
        // epilogue: scale by z, store float4 along n
        const float z0 = zs[4 * ty], z1 = zs[4 * ty + 1], z2 = zs[4 * ty + 2], z3 = zs[4 * ty + 3];
#pragma unroll
        for (int s = 0; s < 8; ++s) {
            const float4 o = make_float4(acc[0][s] * z0, acc[1][s] * z1,
                                         acc[2][s] * z2, acc[3][s] * z3);
            *reinterpret_cast<float4*>(Ob + (size_t)(8 * tx + s) * NN + n0 + 4 * ty) = o;
        }
    }
}

extern "C" void kernel_launch(void* const* d_in, const int* in_sizes, int n_in,
                              void* d_out, int out_size, void* d_ws, size_t ws_size,
                              hipStream_t stream) {
    const float* q = (const float*)d_in[0];
    const float* k = (const float*)d_in[1];
    const float* v = (const float*)d_in[2];
    float* out = (float*)d_out;
    float* KV = (float*)d_ws;                       // B*D*D floats
    float* KS = KV + BD * DD * DD;                  // B*D floats
    hipMemsetAsync(d_ws, 0, (size_t)(BD * DD * DD + BD * DD) * sizeof(float), stream);
    k1_kv<<<dim3(64, BD), 256, 0, stream>>>(k, v, KV, KS);
    k2_out<<<dim3(32, BD), 256, 0, stream>>>(q, KV, KS, out);
}